// Round 1
// baseline (2085.600 us; speedup 1.0000x reference)
//
#include <hip/hip_runtime.h>
#include <cmath>

typedef _Float16 v8h __attribute__((ext_vector_type(8)));
typedef float v4f __attribute__((ext_vector_type(4)));

#define DEV __device__ __forceinline__

constexpr int NWG = 256;  // persistent grid: one WG per CU guaranteed resident

// token index map for shifted-window partition: window-order row m -> spatial token l
DEV int win_map(int m) {
  int w = m >> 6, tok = m & 63;
  int r = ((w >> 1) * 8 + (tok >> 3) + 4) & 15;
  int c = ((w & 1) * 8 + (tok & 7) + 4) & 15;
  return r * 16 + c;
}

// A-row loader. MAP 0: identity rows (stride K). MAP 1: window-shift map (K=384).
// MAP 2: patch-embed im2col gather from x (1,3,256,256), K=768, j=(inc,p,q).
template<int MAP>
DEV float4 loadA4(const float* __restrict__ A, int m, int k, int K) {
  if constexpr (MAP == 0) {
    return *(const float4*)(A + (size_t)m * K + k);
  } else if constexpr (MAP == 1) {
    return *(const float4*)(A + (size_t)win_map(m) * 384 + k);
  } else {
    int h = m >> 4, w = m & 15;
    int inc = k >> 8, rem = k & 255, p = rem >> 4, q = rem & 15;
    return *(const float4*)(A + inc * 65536 + (h * 16 + p) * 256 + w * 16 + q);
  }
}

// one shared-memory arena for all stages (max ~43 KB -> >=3 WG/CU LDS capacity)
union SMem {
  struct {
    _Float16 As[32][72];   // BM<=32, BKP=72 (144B rows, ~2-way banks)
    _Float16 Ws[64][72];   // BN<=64
    float redS[256], redQ[256];
    float lmean[32], lrstd[32];
  } g;
  struct {
    float qs[64][33], ks[64][33], vs[64][33];
    float ps[64][68];
    float rbias[225];
    int labv[64];
  } at;
  struct { float hs[2][384]; } d1;
  struct { float d1s[3][256]; float wcol[3][16]; float srow[16]; } d2;
};

// ---- grid-wide barrier (hand-rolled; all NWG WGs are resident by construction) ----
// release: __syncthreads drains each wave's stores to the XCD L2; __threadfence
// (agent acq_rel) writes back L2 so other XCDs can see the data. poll is a RELAXED
// agent atomic load (coherent, but no per-poll cache inv); one acquire fence on exit.
DEV void gridbar(unsigned* cnt, unsigned* flag, unsigned& gen) {
  __syncthreads();
  if (threadIdx.x == 0) {
    __threadfence();
    unsigned target = ++gen;
    unsigned prev = __hip_atomic_fetch_add(cnt, 1u, __ATOMIC_ACQ_REL, __HIP_MEMORY_SCOPE_AGENT);
    if (prev == NWG - 1) {
      __hip_atomic_store(cnt, 0u, __ATOMIC_RELAXED, __HIP_MEMORY_SCOPE_AGENT);
      __hip_atomic_store(flag, target, __ATOMIC_RELEASE, __HIP_MEMORY_SCOPE_AGENT);
    } else {
      while (__hip_atomic_load(flag, __ATOMIC_RELAXED, __HIP_MEMORY_SCOPE_AGENT) < target)
        __builtin_amdgcn_s_sleep(2);
    }
    __threadfence();
  }
  __syncthreads();
}

// C[m,n] = epilogue( dot(LNopt(A[maprow(m)]), W[n]) ), grid-stride over tiles.
// EPI 0: plain. 1: +bias[n]+resid. 2: gelu(.+bias[n]). 3: transposed patch store.
template<int WAVES_M, int WAVES_N, int WN, int MAP, bool LN, int EPI>
DEV void gemm_stage(SMem& sm, const float* __restrict__ A, const float* __restrict__ W,
                    const float* __restrict__ bias,
                    const float* __restrict__ lnw, const float* __restrict__ lnb,
                    const float* __restrict__ resid, const float* __restrict__ aux,
                    float* __restrict__ Cout, int N, int K) {
  constexpr int BM = WAVES_M * 16;
  constexpr int BN = WAVES_N * WN * 16;
  constexpr int BK = 64;
  static_assert(BM <= 32 && BN <= 64, "SMem capacity");
  auto& As = sm.g.As;
  auto& Ws = sm.g.Ws;

  const int t = threadIdx.x;
  const int wave = t >> 6, lane = t & 63;
  const int wm = wave % WAVES_M;
  const int wn = wave / WAVES_M;
  const int mBase = wm * 16;
  const int nBase = wn * (WN * 16);
  const int tilesX = N / BN;
  const int tiles = tilesX * (256 / BM);

  for (int tile = blockIdx.x; tile < tiles; tile += NWG) {
    const int m0 = (tile / tilesX) * BM;
    const int n0 = (tile % tilesX) * BN;

    if constexpr (LN) {
      constexpr int PARTS = 256 / BM;
      int r = t / PARTS, part = t % PARTS;
      int chunk = K / PARTS;
      float s = 0.f, sq = 0.f;
      for (int k = part * chunk; k < (part + 1) * chunk; k += 4) {
        float4 v = loadA4<MAP>(A, m0 + r, k, K);
        s += v.x + v.y + v.z + v.w;
        sq += v.x * v.x + v.y * v.y + v.z * v.z + v.w * v.w;
      }
      sm.g.redS[t] = s; sm.g.redQ[t] = sq;
      __syncthreads();
      if (t < BM) {
        float ss = 0.f, qq = 0.f;
        for (int p2 = 0; p2 < PARTS; ++p2) { ss += sm.g.redS[t * PARTS + p2]; qq += sm.g.redQ[t * PARTS + p2]; }
        float mean = ss / K;
        float var = qq / K - mean * mean;
        sm.g.lmean[t] = mean;
        sm.g.lrstd[t] = rsqrtf(var + 1e-5f);
      }
      __syncthreads();
    }

    v4f acc[WN] = {};

    for (int k0 = 0; k0 < K; k0 += BK) {
      constexpr int AREP = (BM * 16) / 256;
#pragma unroll
      for (int i = 0; i < AREP; ++i) {
        int idx = t + i * 256;
        int row = idx >> 4;
        int kc = (idx & 15) * 4;
        float4 v = loadA4<MAP>(A, m0 + row, k0 + kc, K);
        if constexpr (LN) {
          float4 lw = *(const float4*)(lnw + k0 + kc);
          float4 lb = *(const float4*)(lnb + k0 + kc);
          float mu = sm.g.lmean[row], rs = sm.g.lrstd[row];
          v.x = (v.x - mu) * rs * lw.x + lb.x;
          v.y = (v.y - mu) * rs * lw.y + lb.y;
          v.z = (v.z - mu) * rs * lw.z + lb.z;
          v.w = (v.w - mu) * rs * lw.w + lb.w;
        }
        _Float16* dst = &As[row][kc];
        dst[0] = (_Float16)v.x; dst[1] = (_Float16)v.y;
        dst[2] = (_Float16)v.z; dst[3] = (_Float16)v.w;
      }
      constexpr int WREP = (BN * 16) / 256;
#pragma unroll
      for (int i = 0; i < WREP; ++i) {
        int idx = t + i * 256;
        int row = idx >> 4;
        int kc = (idx & 15) * 4;
        float4 v = *(const float4*)(W + (size_t)(n0 + row) * K + k0 + kc);
        _Float16* dst = &Ws[row][kc];
        dst[0] = (_Float16)v.x; dst[1] = (_Float16)v.y;
        dst[2] = (_Float16)v.z; dst[3] = (_Float16)v.w;
      }
      __syncthreads();
#pragma unroll
      for (int kk = 0; kk < BK; kk += 32) {
        v8h af = *(const v8h*)&As[mBase + (lane & 15)][kk + (lane >> 4) * 8];
#pragma unroll
        for (int nt = 0; nt < WN; ++nt) {
          v8h bf = *(const v8h*)&Ws[nBase + nt * 16 + (lane & 15)][kk + (lane >> 4) * 8];
          acc[nt] = __builtin_amdgcn_mfma_f32_16x16x32_f16(af, bf, acc[nt], 0, 0, 0);
        }
      }
      __syncthreads();
    }

    const int quad = lane >> 4;
    const int col = lane & 15;
#pragma unroll
    for (int nt = 0; nt < WN; ++nt) {
      int n = n0 + nBase + nt * 16 + col;
#pragma unroll
      for (int r2 = 0; r2 < 4; ++r2) {
        int m = m0 + mBase + quad * 4 + r2;
        float v = acc[nt][r2];
        if constexpr (EPI == 0) {
          Cout[(size_t)m * N + n] = v;
        } else if constexpr (EPI == 1) {
          Cout[(size_t)m * N + n] = resid[(size_t)m * N + n] + v + bias[n];
        } else if constexpr (EPI == 2) {
          float z = v + bias[n];
          Cout[(size_t)m * N + n] = 0.5f * z * (1.0f + erff(z * 0.70710678118654752f));
        } else {
          Cout[n * 256 + m] = v + bias[n] + aux[n * 256 + m];
        }
      }
    }
  }
}

// windowed attention: unit u = (window, head); 48 units, one per WG.
DEV void attn_stage(SMem& sm, const float* __restrict__ qkv, const float* __restrict__ rpb,
                    float* __restrict__ obuf) {
  const int t = threadIdx.x;
  for (int u = blockIdx.x; u < 48; u += NWG) {
    const int w = u & 3, head = u >> 2;

    for (int idx = t; idx < 2048; idx += 256) {
      int tok = idx >> 5, d = idx & 31;
      int base = (w * 64 + tok) * 1152 + head * 32 + d;
      sm.at.qs[tok][d] = qkv[base];
      sm.at.ks[tok][d] = qkv[base + 384];
      sm.at.vs[tok][d] = qkv[base + 768];
    }
    for (int idx = t; idx < 225; idx += 256) sm.at.rbias[idx] = rpb[idx * 12 + head];
    if (t < 64) {
      int r = (w >> 1) * 8 + (t >> 3), c = (w & 1) * 8 + (t & 7);
      int lr = r < 8 ? 0 : (r < 12 ? 1 : 2);
      int lc = c < 8 ? 0 : (c < 12 ? 1 : 2);
      sm.at.labv[t] = lr * 3 + lc;
    }
    __syncthreads();

    const int tx = t & 15, ty = t >> 4;
    float acc[4][4] = {};
    for (int d = 0; d < 32; ++d) {
      float a[4], b[4];
#pragma unroll
      for (int ii = 0; ii < 4; ++ii) a[ii] = sm.at.qs[ty * 4 + ii][d];
#pragma unroll
      for (int jj = 0; jj < 4; ++jj) b[jj] = sm.at.ks[tx * 4 + jj][d];
#pragma unroll
      for (int ii = 0; ii < 4; ++ii)
#pragma unroll
        for (int jj = 0; jj < 4; ++jj) acc[ii][jj] += a[ii] * b[jj];
    }
    const float scale = 0.17677669529663687f;  // 32^-0.5
#pragma unroll
    for (int ii = 0; ii < 4; ++ii) {
      int i = ty * 4 + ii;
      int yi = i >> 3, xi = i & 7, li = sm.at.labv[i];
      float pv[4];
      float mx = -1e30f;
#pragma unroll
      for (int jj = 0; jj < 4; ++jj) {
        int j = tx * 4 + jj;
        int yj = j >> 3, xj = j & 7;
        int ri = (yi - yj + 7) * 15 + (xi - xj + 7);
        float s = acc[ii][jj] * scale + sm.at.rbias[ri] + (li == sm.at.labv[j] ? 0.f : -100.f);
        pv[jj] = s;
        mx = fmaxf(mx, s);
      }
      for (int off = 1; off < 16; off <<= 1) mx = fmaxf(mx, __shfl_xor(mx, off));
      float sum = 0.f;
#pragma unroll
      for (int jj = 0; jj < 4; ++jj) { pv[jj] = expf(pv[jj] - mx); sum += pv[jj]; }
      for (int off = 1; off < 16; off <<= 1) sum += __shfl_xor(sum, off);
      float inv = 1.0f / sum;
#pragma unroll
      for (int jj = 0; jj < 4; ++jj) sm.at.ps[i][tx * 4 + jj] = pv[jj] * inv;
    }
    __syncthreads();

    float o2[4][2] = {};
    for (int j = 0; j < 64; ++j) {
      float v0 = sm.at.vs[j][tx * 2 + 0], v1 = sm.at.vs[j][tx * 2 + 1];
#pragma unroll
      for (int ii = 0; ii < 4; ++ii) {
        float p = sm.at.ps[ty * 4 + ii][j];
        o2[ii][0] += p * v0;
        o2[ii][1] += p * v1;
      }
    }
#pragma unroll
    for (int ii = 0; ii < 4; ++ii) {
      int l = win_map(w * 64 + ty * 4 + ii);
      obuf[l * 384 + head * 32 + tx * 2 + 0] = o2[ii][0];
      obuf[l * 384 + head * 32 + tx * 2 + 1] = o2[ii][1];
    }
    __syncthreads();
  }
}

// decoder stage 1: WGs 0..127 -> d1 (2 tokens each); WGs 128..131 -> skip rows.
DEV void dec1_stage(SMem& sm, const float* __restrict__ hfin,
                    const float* __restrict__ wgt, const float* __restrict__ bvec,
                    const float* __restrict__ bnw, const float* __restrict__ bnb,
                    float* __restrict__ d1,
                    const float* __restrict__ sw, const float* __restrict__ sb,
                    float* __restrict__ skipb) {
  const int t = threadIdx.x;
  const int wg = blockIdx.x;
  if (wg < 128) {
    const int l0 = wg * 2;
    for (int idx = t; idx < 768; idx += 256) {
      int pi = idx / 384, c = idx % 384;
      sm.d1.hs[pi][c] = hfin[(l0 + pi) * 384 + c];
    }
    __syncthreads();
    const float invs = rsqrtf(1.0f + 1e-5f);
    const int kk = t >> 4, ll = t & 15;
    for (int o = 0; o < 3; ++o) {
      float a0 = 0.f, a1 = 0.f;
      for (int c = 0; c < 384; ++c) {
        float wv = wgt[c * 768 + o * 256 + t];
        a0 += sm.d1.hs[0][c] * wv;
        a1 += sm.d1.hs[1][c] * wv;
      }
      float swv = bnw[o] * invs, bb = bvec[o], sbv = bnb[o];
      float v0 = fmaxf((a0 + bb) * swv + sbv, 0.f);
      float v1 = fmaxf((a1 + bb) * swv + sbv, 0.f);
#pragma unroll
      for (int pi = 0; pi < 2; ++pi) {
        int l = l0 + pi;
        int hh = l >> 4, wq = l & 15;
        d1[o * 65536 + (hh * 16 + kk) * 256 + (wq * 16 + ll)] = pi ? v1 : v0;
      }
    }
  } else if (wg < 132) {
    const int o = wg - 128;
    float acc = 0.f;
    for (int c = 0; c < 384; ++c) acc += hfin[t * 384 + c] * sw[o * 384 + c];
    skipb[o * 256 + t] = acc + sb[o];
  }
}

// decoder stage 2: 16384 (y,o) row units, grid-stride (64 units per WG).
DEV void dec2_stage(SMem& sm, const float* __restrict__ d1, const float* __restrict__ w2,
                    const float* __restrict__ b2, const float* __restrict__ bnw,
                    const float* __restrict__ bnb, const float* __restrict__ skipb,
                    float* __restrict__ out) {
  const int t = threadIdx.x;
  for (int u = blockIdx.x; u < 16384; u += NWG) {
    const int y = u & 4095, o = u >> 12;
    const int h2 = y >> 4, k = y & 15;
    for (int idx = t; idx < 768; idx += 256) {
      int c = idx >> 8, wi = idx & 255;
      sm.d2.d1s[c][wi] = d1[c * 65536 + h2 * 256 + wi];
    }
    if (t < 48) {
      int c = t >> 4, l2 = t & 15;
      sm.d2.wcol[c][l2] = w2[c * 1024 + o * 256 + k * 16 + l2];
    }
    if (t < 16) {
      const float dy = 15.0f / 4095.0f;
      float s = y * dy;
      int y0 = min((int)s, 15);
      int y1 = min(y0 + 1, 15);
      float wy = s - (float)y0;
      float a0 = skipb[o * 256 + y0 * 16 + t];
      float a1 = skipb[o * 256 + y1 * 16 + t];
      sm.d2.srow[t] = a0 + (a1 - a0) * wy;
    }
    __syncthreads();
    const float invs = rsqrtf(1.0f + 1e-5f);
    const float swv = bnw[o] * invs;
    const float base = b2[o] * swv + bnb[o];
    const float dx = 15.0f / 4095.0f;
    const size_t obase = ((size_t)o << 24) + ((size_t)y << 12);
#pragma unroll
    for (int rep = 0; rep < 4; ++rep) {
      int x4 = t + rep * 256;
      int x = x4 * 4;
      int wi = x >> 4;
      int l2b = x & 15;
      float vals[4];
#pragma unroll
      for (int e = 0; e < 4; ++e) {
        int l2 = l2b + e;
        float v = sm.d2.d1s[0][wi] * sm.d2.wcol[0][l2] + sm.d2.d1s[1][wi] * sm.d2.wcol[1][l2] +
                  sm.d2.d1s[2][wi] * sm.d2.wcol[2][l2];
        v = v * swv + base;
        float s = (float)(x + e) * dx;
        int x0 = min((int)s, 15);
        int x1 = min(x0 + 1, 15);
        float wx = s - (float)x0;
        vals[e] = v + sm.d2.srow[x0] + (sm.d2.srow[x1] - sm.d2.srow[x0]) * wx;
      }
      *(float4*)&out[obase + x] = make_float4(vals[0], vals[1], vals[2], vals[3]);
    }
    __syncthreads();
  }
}

struct MegaP {
  const float *x, *patch_w, *patch_b, *pos;
  const float *ln1w, *ln1b, *qkvw, *projw, *projb, *rpb, *ln2w, *ln2b;
  const float *fc1w, *fc1b, *fc2w, *fc2b;
  const float *skipw, *skipbi, *dt1w, *dt1b, *bn1w, *bn1b, *dt2w, *dt2b, *bn2w, *bn2b;
  float *out, *ws;
  unsigned *cnt, *flag;
};

// whole network: 1 dispatch, 62 grid barriers instead of 52 kernel launches.
__launch_bounds__(256)
__global__ void swin_mega(MegaP p) {
  __shared__ SMem sm;
  unsigned gen = 0;

  float* h    = p.ws;                // 98304   (256 x 384, "buggy-flatten" layout)
  float* qkvb = p.ws + 98304;        // 294912
  float* obuf = p.ws + 393216;       // 98304
  float* zb   = p.ws + 491520;       // 393216
  float* d1b  = p.ws + 884736;       // 196608
  float* skb  = p.ws + 1081344;      // 1024

  // patch embed: M=256 (h,w), N=384 (c), K=768; transposed store + pos add
  gemm_stage<2, 2, 2, 2, false, 3>(sm, p.x, p.patch_w, p.patch_b, nullptr, nullptr,
                                   nullptr, p.pos, h, 384, 768);
  gridbar(p.cnt, p.flag, gen);

#pragma unroll 1
  for (int b = 0; b < 12; ++b) {
    // qkv: LN1 + window-shift rows, N=1152, K=384 (144 tiles)
    gemm_stage<2, 2, 2, 1, true, 0>(sm, h, p.qkvw + (size_t)b * 442368, nullptr,
                                    p.ln1w + b * 384, p.ln1b + b * 384,
                                    nullptr, nullptr, qkvb, 1152, 384);
    gridbar(p.cnt, p.flag, gen);
    attn_stage(sm, qkvb, p.rpb + b * 2700, obuf);
    gridbar(p.cnt, p.flag, gen);
    // proj: + bias + residual(h) -> h (96 tiles)
    gemm_stage<1, 4, 1, 0, false, 1>(sm, obuf, p.projw + (size_t)b * 147456,
                                     p.projb + b * 384, nullptr, nullptr,
                                     h, nullptr, h, 384, 384);
    gridbar(p.cnt, p.flag, gen);
    // fc1: LN2 + gelu, N=1536, K=384 (192 tiles)
    gemm_stage<2, 2, 2, 0, true, 2>(sm, h, p.fc1w + (size_t)b * 589824,
                                    p.fc1b + b * 1536, p.ln2w + b * 384, p.ln2b + b * 384,
                                    nullptr, nullptr, zb, 1536, 384);
    gridbar(p.cnt, p.flag, gen);
    // fc2: + bias + residual(h) -> h, N=384, K=1536 (96 tiles)
    gemm_stage<1, 4, 1, 0, false, 1>(sm, zb, p.fc2w + (size_t)b * 589824,
                                     p.fc2b + b * 384, nullptr, nullptr,
                                     h, nullptr, h, 384, 1536);
    gridbar(p.cnt, p.flag, gen);
  }

  dec1_stage(sm, h, p.dt1w, p.dt1b, p.bn1w, p.bn1b, d1b, p.skipw, p.skipbi, skb);
  gridbar(p.cnt, p.flag, gen);
  dec2_stage(sm, d1b, p.dt2w, p.dt2b, p.bn2w, p.bn2b, skb, p.out);
}

// barrier state lives in poisoned workspace -> must re-zero every replay.
__global__ void init_bar_k(unsigned* bar) {
  if (threadIdx.x < 96) bar[threadIdx.x] = 0;
}

extern "C" void kernel_launch(void* const* d_in, const int* in_sizes, int n_in,
                              void* d_out, int out_size, void* d_ws, size_t ws_size,
                              hipStream_t stream) {
  float* ws = (float*)d_ws;
  unsigned* bar = (unsigned*)(ws + 1082368);  // past skb; 8-byte state, padded

  MegaP p;
  p.x       = (const float*)d_in[0];
  p.patch_w = (const float*)d_in[1];
  p.patch_b = (const float*)d_in[2];
  p.pos     = (const float*)d_in[3];
  p.ln1w    = (const float*)d_in[4];
  p.ln1b    = (const float*)d_in[5];
  p.qkvw    = (const float*)d_in[6];
  p.projw   = (const float*)d_in[7];
  p.projb   = (const float*)d_in[8];
  p.rpb     = (const float*)d_in[9];
  p.ln2w    = (const float*)d_in[10];
  p.ln2b    = (const float*)d_in[11];
  p.fc1w    = (const float*)d_in[12];
  p.fc1b    = (const float*)d_in[13];
  p.fc2w    = (const float*)d_in[14];
  p.fc2b    = (const float*)d_in[15];
  p.skipw   = (const float*)d_in[16];
  p.skipbi  = (const float*)d_in[17];
  p.dt1w    = (const float*)d_in[18];
  p.dt1b    = (const float*)d_in[19];
  p.bn1w    = (const float*)d_in[20];
  p.bn1b    = (const float*)d_in[21];
  p.dt2w    = (const float*)d_in[22];
  p.dt2b    = (const float*)d_in[23];
  p.bn2w    = (const float*)d_in[24];
  p.bn2b    = (const float*)d_in[25];
  p.out = (float*)d_out;
  p.ws  = ws;
  p.cnt  = bar;
  p.flag = bar + 64;  // separate cachelines: arrive traffic vs poll traffic

  init_bar_k<<<1, 128, 0, stream>>>(bar);
  swin_mega<<<NWG, 256, 0, stream>>>(p);
}

// Round 3
// 1320.352 us; speedup vs baseline: 1.5796x; 1.5796x over previous
//
#include <hip/hip_runtime.h>
#include <cmath>

typedef _Float16 v8h __attribute__((ext_vector_type(8)));
typedef float v4f __attribute__((ext_vector_type(4)));

#define DEV __device__ __forceinline__

constexpr int NWG = 256;  // persistent grid: one WG per CU guaranteed resident

// ---- coherent (agent-scope, MALL-backed) access helpers for inter-stage data ----
// relaxed agent atomics compile to sc1 cache-bypassing loads/stores: they read/write
// the memory-side cache (coherence point across XCDs), so no wbl2/inv fences needed.
DEV float ld1(const float* p) {
  unsigned v = __hip_atomic_load((const unsigned*)p, __ATOMIC_RELAXED, __HIP_MEMORY_SCOPE_AGENT);
  float r; __builtin_memcpy(&r, &v, 4); return r;
}
DEV float2 ld2(const float* p) {
  unsigned long long v = __hip_atomic_load((const unsigned long long*)p, __ATOMIC_RELAXED,
                                           __HIP_MEMORY_SCOPE_AGENT);
  float2 r; __builtin_memcpy(&r, &v, 8); return r;
}
DEV float4 ld4(const float* p) {
  float2 a = ld2(p), b = ld2(p + 2);
  return make_float4(a.x, a.y, b.x, b.y);
}
DEV void st1(float* p, float v) {
  unsigned u; __builtin_memcpy(&u, &v, 4);
  __hip_atomic_store((unsigned*)p, u, __ATOMIC_RELAXED, __HIP_MEMORY_SCOPE_AGENT);
}
DEV void st2(float* p, float a, float b) {
  float2 t = make_float2(a, b);
  unsigned long long u; __builtin_memcpy(&u, &t, 8);
  __hip_atomic_store((unsigned long long*)p, u, __ATOMIC_RELAXED, __HIP_MEMORY_SCOPE_AGENT);
}

// token index map for shifted-window partition: window-order row m -> spatial token l
DEV int win_map(int m) {
  int w = m >> 6, tok = m & 63;
  int r = ((w >> 1) * 8 + (tok >> 3) + 4) & 15;
  int c = ((w & 1) * 8 + (tok & 7) + 4) & 15;
  return r * 16 + c;
}

// A-row loader. MAP 0: identity rows (stride K), coherent (activations).
// MAP 1: window-shift map (K=384), coherent. MAP 2: patch-embed im2col gather from
// x (1,3,256,256), K=768 — read-only input, normal cached loads.
template<int MAP>
DEV float4 loadA4(const float* __restrict__ A, int m, int k, int K) {
  if constexpr (MAP == 0) {
    return ld4(A + (size_t)m * K + k);
  } else if constexpr (MAP == 1) {
    return ld4(A + (size_t)win_map(m) * 384 + k);
  } else {
    int h = m >> 4, w = m & 15;
    int inc = k >> 8, rem = k & 255, p = rem >> 4, q = rem & 15;
    return *(const float4*)(A + inc * 65536 + (h * 16 + p) * 256 + w * 16 + q);
  }
}

// one shared-memory arena for all stages (max ~44 KB)
union SMem {
  struct {
    _Float16 As[32][72];   // BM<=32, BKP=72 (144B rows, ~2-way banks)
    _Float16 Ws[64][72];   // BN<=64
    float redS[256], redQ[256];
    float lmean[32], lrstd[32];
  } g;
  struct {
    float qs[64][33], ks[64][33], vs[64][33];
    float ps[64][68];
    float rbias[225];
    int labv[64];
  } at;
  struct { float hs[2][384]; } d1;
  struct { float d1s[3][256]; float w2s[3072]; float srow[1024]; } d2;
};

// ---- grid-wide barrier, fence-free ----
// __syncthreads() drains vmcnt(0): all of this WG's sc1 stores have completed at the
// MALL before the leader arrives. Flag set only after all 256 WGs arrived, so all
// inter-stage data is globally visible. Readers use sc1 loads -> no invalidate needed.
DEV void gridbar(unsigned* cnt, unsigned* flag, unsigned& gen) {
  __syncthreads();
  if (threadIdx.x == 0) {
    unsigned target = ++gen;
    unsigned prev = __hip_atomic_fetch_add(cnt, 1u, __ATOMIC_RELAXED, __HIP_MEMORY_SCOPE_AGENT);
    if (prev == NWG - 1) {
      __hip_atomic_store(cnt, 0u, __ATOMIC_RELAXED, __HIP_MEMORY_SCOPE_AGENT);
      __hip_atomic_store(flag, target, __ATOMIC_RELAXED, __HIP_MEMORY_SCOPE_AGENT);
    } else {
      while (__hip_atomic_load(flag, __ATOMIC_RELAXED, __HIP_MEMORY_SCOPE_AGENT) < target)
        __builtin_amdgcn_s_sleep(4);
    }
  }
  __syncthreads();
}

// C[m,n] = epilogue( dot(LNopt(A[maprow(m)]), W[n]) ), grid-stride over tiles.
// EPI 0: plain. 1: +bias[n]+resid. 2: gelu(.+bias[n]). 3: transposed patch store.
// Activations (A for MAP0/1, resid, C stores) coherent; weights/bias/ln normal.
template<int WAVES_M, int WAVES_N, int WN, int MAP, bool LN, int EPI>
DEV void gemm_stage(SMem& sm, const float* __restrict__ A, const float* __restrict__ W,
                    const float* __restrict__ bias,
                    const float* __restrict__ lnw, const float* __restrict__ lnb,
                    const float* __restrict__ resid, const float* __restrict__ aux,
                    float* __restrict__ Cout, int N, int K) {
  constexpr int BM = WAVES_M * 16;
  constexpr int BN = WAVES_N * WN * 16;
  constexpr int BK = 64;
  static_assert(BM <= 32 && BN <= 64, "SMem capacity");
  auto& As = sm.g.As;
  auto& Ws = sm.g.Ws;

  const int t = threadIdx.x;
  const int wave = t >> 6, lane = t & 63;
  const int wm = wave % WAVES_M;
  const int wn = wave / WAVES_M;
  const int mBase = wm * 16;
  const int nBase = wn * (WN * 16);
  const int tilesX = N / BN;
  const int tiles = tilesX * (256 / BM);

  for (int tile = blockIdx.x; tile < tiles; tile += NWG) {
    const int m0 = (tile / tilesX) * BM;
    const int n0 = (tile % tilesX) * BN;

    if constexpr (LN) {
      constexpr int PARTS = 256 / BM;
      int r = t / PARTS, part = t % PARTS;
      int chunk = K / PARTS;
      float s = 0.f, sq = 0.f;
      for (int k = part * chunk; k < (part + 1) * chunk; k += 4) {
        float4 v = loadA4<MAP>(A, m0 + r, k, K);
        s += v.x + v.y + v.z + v.w;
        sq += v.x * v.x + v.y * v.y + v.z * v.z + v.w * v.w;
      }
      sm.g.redS[t] = s; sm.g.redQ[t] = sq;
      __syncthreads();
      if (t < BM) {
        float ss = 0.f, qq = 0.f;
        for (int p2 = 0; p2 < PARTS; ++p2) { ss += sm.g.redS[t * PARTS + p2]; qq += sm.g.redQ[t * PARTS + p2]; }
        float mean = ss / K;
        float var = qq / K - mean * mean;
        sm.g.lmean[t] = mean;
        sm.g.lrstd[t] = rsqrtf(var + 1e-5f);
      }
      __syncthreads();
    }

    v4f acc[WN] = {};

    for (int k0 = 0; k0 < K; k0 += BK) {
      constexpr int AREP = (BM * 16) / 256;
#pragma unroll
      for (int i = 0; i < AREP; ++i) {
        int idx = t + i * 256;
        int row = idx >> 4;
        int kc = (idx & 15) * 4;
        float4 v = loadA4<MAP>(A, m0 + row, k0 + kc, K);
        if constexpr (LN) {
          float4 lw = *(const float4*)(lnw + k0 + kc);
          float4 lb = *(const float4*)(lnb + k0 + kc);
          float mu = sm.g.lmean[row], rs = sm.g.lrstd[row];
          v.x = (v.x - mu) * rs * lw.x + lb.x;
          v.y = (v.y - mu) * rs * lw.y + lb.y;
          v.z = (v.z - mu) * rs * lw.z + lb.z;
          v.w = (v.w - mu) * rs * lw.w + lb.w;
        }
        _Float16* dst = &As[row][kc];
        dst[0] = (_Float16)v.x; dst[1] = (_Float16)v.y;
        dst[2] = (_Float16)v.z; dst[3] = (_Float16)v.w;
      }
      constexpr int WREP = (BN * 16) / 256;
#pragma unroll
      for (int i = 0; i < WREP; ++i) {
        int idx = t + i * 256;
        int row = idx >> 4;
        int kc = (idx & 15) * 4;
        float4 v = *(const float4*)(W + (size_t)(n0 + row) * K + k0 + kc);
        _Float16* dst = &Ws[row][kc];
        dst[0] = (_Float16)v.x; dst[1] = (_Float16)v.y;
        dst[2] = (_Float16)v.z; dst[3] = (_Float16)v.w;
      }
      __syncthreads();
#pragma unroll
      for (int kk = 0; kk < BK; kk += 32) {
        v8h af = *(const v8h*)&As[mBase + (lane & 15)][kk + (lane >> 4) * 8];
#pragma unroll
        for (int nt = 0; nt < WN; ++nt) {
          v8h bf = *(const v8h*)&Ws[nBase + nt * 16 + (lane & 15)][kk + (lane >> 4) * 8];
          acc[nt] = __builtin_amdgcn_mfma_f32_16x16x32_f16(af, bf, acc[nt], 0, 0, 0);
        }
      }
      __syncthreads();
    }

    const int quad = lane >> 4;
    const int col = lane & 15;
#pragma unroll
    for (int nt = 0; nt < WN; ++nt) {
      int n = n0 + nBase + nt * 16 + col;
#pragma unroll
      for (int r2 = 0; r2 < 4; ++r2) {
        int m = m0 + mBase + quad * 4 + r2;
        float v = acc[nt][r2];
        if constexpr (EPI == 0) {
          st1(Cout + (size_t)m * N + n, v);
        } else if constexpr (EPI == 1) {
          st1(Cout + (size_t)m * N + n, ld1(resid + (size_t)m * N + n) + v + bias[n]);
        } else if constexpr (EPI == 2) {
          float z = v + bias[n];
          st1(Cout + (size_t)m * N + n, 0.5f * z * (1.0f + erff(z * 0.70710678118654752f)));
        } else {
          st1(Cout + n * 256 + m, v + bias[n] + aux[n * 256 + m]);
        }
      }
    }
  }
}

// windowed attention: unit u = (window, head); 48 units, one per WG.
DEV void attn_stage(SMem& sm, const float* __restrict__ qkv, const float* __restrict__ rpb,
                    float* __restrict__ obuf) {
  const int t = threadIdx.x;
  for (int u = blockIdx.x; u < 48; u += NWG) {
    const int w = u & 3, head = u >> 2;

    for (int idx = t; idx < 1024; idx += 256) {
      int tok = idx >> 4, d2 = (idx & 15) * 2;
      int base = (w * 64 + tok) * 1152 + head * 32 + d2;
      float2 q2 = ld2(qkv + base);
      float2 k2 = ld2(qkv + base + 384);
      float2 v2 = ld2(qkv + base + 768);
      sm.at.qs[tok][d2] = q2.x; sm.at.qs[tok][d2 + 1] = q2.y;
      sm.at.ks[tok][d2] = k2.x; sm.at.ks[tok][d2 + 1] = k2.y;
      sm.at.vs[tok][d2] = v2.x; sm.at.vs[tok][d2 + 1] = v2.y;
    }
    for (int idx = t; idx < 225; idx += 256) sm.at.rbias[idx] = rpb[idx * 12 + head];
    if (t < 64) {
      int r = (w >> 1) * 8 + (t >> 3), c = (w & 1) * 8 + (t & 7);
      int lr = r < 8 ? 0 : (r < 12 ? 1 : 2);
      int lc = c < 8 ? 0 : (c < 12 ? 1 : 2);
      sm.at.labv[t] = lr * 3 + lc;
    }
    __syncthreads();

    const int tx = t & 15, ty = t >> 4;
    float acc[4][4] = {};
    for (int d = 0; d < 32; ++d) {
      float a[4], b[4];
#pragma unroll
      for (int ii = 0; ii < 4; ++ii) a[ii] = sm.at.qs[ty * 4 + ii][d];
#pragma unroll
      for (int jj = 0; jj < 4; ++jj) b[jj] = sm.at.ks[tx * 4 + jj][d];
#pragma unroll
      for (int ii = 0; ii < 4; ++ii)
#pragma unroll
        for (int jj = 0; jj < 4; ++jj) acc[ii][jj] += a[ii] * b[jj];
    }
    const float scale = 0.17677669529663687f;  // 32^-0.5
#pragma unroll
    for (int ii = 0; ii < 4; ++ii) {
      int i = ty * 4 + ii;
      int yi = i >> 3, xi = i & 7, li = sm.at.labv[i];
      float pv[4];
      float mx = -1e30f;
#pragma unroll
      for (int jj = 0; jj < 4; ++jj) {
        int j = tx * 4 + jj;
        int yj = j >> 3, xj = j & 7;
        int ri = (yi - yj + 7) * 15 + (xi - xj + 7);
        float s = acc[ii][jj] * scale + sm.at.rbias[ri] + (li == sm.at.labv[j] ? 0.f : -100.f);
        pv[jj] = s;
        mx = fmaxf(mx, s);
      }
      for (int off = 1; off < 16; off <<= 1) mx = fmaxf(mx, __shfl_xor(mx, off));
      float sum = 0.f;
#pragma unroll
      for (int jj = 0; jj < 4; ++jj) { pv[jj] = expf(pv[jj] - mx); sum += pv[jj]; }
      for (int off = 1; off < 16; off <<= 1) sum += __shfl_xor(sum, off);
      float inv = 1.0f / sum;
#pragma unroll
      for (int jj = 0; jj < 4; ++jj) sm.at.ps[i][tx * 4 + jj] = pv[jj] * inv;
    }
    __syncthreads();

    float o2[4][2] = {};
    for (int j = 0; j < 64; ++j) {
      float v0 = sm.at.vs[j][tx * 2 + 0], v1 = sm.at.vs[j][tx * 2 + 1];
#pragma unroll
      for (int ii = 0; ii < 4; ++ii) {
        float p = sm.at.ps[ty * 4 + ii][j];
        o2[ii][0] += p * v0;
        o2[ii][1] += p * v1;
      }
    }
#pragma unroll
    for (int ii = 0; ii < 4; ++ii) {
      int l = win_map(w * 64 + ty * 4 + ii);
      st2(obuf + l * 384 + head * 32 + tx * 2, o2[ii][0], o2[ii][1]);
    }
    __syncthreads();
  }
}

// decoder stage 1: WGs 0..127 -> d1 (2 tokens each); WGs 128..131 -> skip rows.
DEV void dec1_stage(SMem& sm, const float* __restrict__ hfin,
                    const float* __restrict__ wgt, const float* __restrict__ bvec,
                    const float* __restrict__ bnw, const float* __restrict__ bnb,
                    float* __restrict__ d1,
                    const float* __restrict__ sw, const float* __restrict__ sb,
                    float* __restrict__ skipb) {
  const int t = threadIdx.x;
  const int wg = blockIdx.x;
  if (wg < 128) {
    const int l0 = wg * 2;
    for (int idx = t; idx < 384; idx += 256) {
      int pi = idx / 192, c2 = (idx % 192) * 2;
      float2 v = ld2(hfin + (l0 + pi) * 384 + c2);
      sm.d1.hs[pi][c2] = v.x; sm.d1.hs[pi][c2 + 1] = v.y;
    }
    __syncthreads();
    const float invs = rsqrtf(1.0f + 1e-5f);
    const int kk = t >> 4, ll = t & 15;
    for (int o = 0; o < 3; ++o) {
      float a0 = 0.f, a1 = 0.f;
      for (int c = 0; c < 384; ++c) {
        float wv = wgt[c * 768 + o * 256 + t];
        a0 += sm.d1.hs[0][c] * wv;
        a1 += sm.d1.hs[1][c] * wv;
      }
      float swv = bnw[o] * invs, bb = bvec[o], sbv = bnb[o];
      float v0 = fmaxf((a0 + bb) * swv + sbv, 0.f);
      float v1 = fmaxf((a1 + bb) * swv + sbv, 0.f);
#pragma unroll
      for (int pi = 0; pi < 2; ++pi) {
        int l = l0 + pi;
        int hh = l >> 4, wq = l & 15;
        st1(d1 + o * 65536 + (hh * 16 + kk) * 256 + (wq * 16 + ll), pi ? v1 : v0);
      }
    }
  } else if (wg < 132) {
    const int o = wg - 128;
    float acc = 0.f;
    for (int c = 0; c < 384; c += 4) {
      float4 hv = ld4(hfin + t * 384 + c);
      const float4 wv = *(const float4*)(sw + o * 384 + c);
      acc += hv.x * wv.x + hv.y * wv.y + hv.z * wv.z + hv.w * wv.w;
    }
    st1(skipb + o * 256 + t, acc + sb[o]);
  }
}

// decoder stage 2: one WG per d1-row-group h2 (256 units); each writes 16 y x 4 o
// output rows (1 MB). d1 row loaded once (was 16x), out stored nontemporal.
DEV void dec2_stage(SMem& sm, const float* __restrict__ d1, const float* __restrict__ w2,
                    const float* __restrict__ b2, const float* __restrict__ bnw,
                    const float* __restrict__ bnb, const float* __restrict__ skipb,
                    float* __restrict__ out) {
  const int t = threadIdx.x;
  const int h2 = blockIdx.x;  // exactly NWG=256 units
  for (int idx = t; idx < 384; idx += 256) {
    int c = idx >> 7, pair = (idx & 127) * 2;
    float2 v = ld2(d1 + c * 65536 + h2 * 256 + pair);
    sm.d2.d1s[c][pair] = v.x; sm.d2.d1s[c][pair + 1] = v.y;
  }
  for (int idx = t; idx < 3072; idx += 256) sm.d2.w2s[idx] = w2[idx];  // [c][o][k][l]
  for (int idx = t; idx < 1024; idx += 256) {
    int o = idx >> 8, k = (idx >> 4) & 15, xc = idx & 15;
    int y = h2 * 16 + k;
    float s = y * (15.0f / 4095.0f);
    int y0 = min((int)s, 15), y1 = min(y0 + 1, 15);
    float wy = s - (float)y0;
    float a0 = ld1(skipb + o * 256 + y0 * 16 + xc);
    float a1 = ld1(skipb + o * 256 + y1 * 16 + xc);
    sm.d2.srow[idx] = a0 + (a1 - a0) * wy;  // [o][k][xc]
  }
  __syncthreads();
  const float invs = rsqrtf(1.0f + 1e-5f);
  const float dx = 15.0f / 4095.0f;
  for (int k = 0; k < 16; ++k) {
    int y = h2 * 16 + k;
    for (int o = 0; o < 4; ++o) {
      const float swv = bnw[o] * invs;
      const float base = b2[o] * swv + bnb[o];
      const float* srow = &sm.d2.srow[o * 256 + k * 16];
      const float* wc0 = &sm.d2.w2s[0 * 1024 + o * 256 + k * 16];
      const float* wc1 = &sm.d2.w2s[1 * 1024 + o * 256 + k * 16];
      const float* wc2 = &sm.d2.w2s[2 * 1024 + o * 256 + k * 16];
      const size_t obase = ((size_t)o << 24) + ((size_t)y << 12);
#pragma unroll
      for (int rep = 0; rep < 4; ++rep) {
        int x = (t + rep * 256) * 4;
        int wi = x >> 4, l2b = x & 15;
        float d0 = sm.d2.d1s[0][wi], d1v = sm.d2.d1s[1][wi], d2v = sm.d2.d1s[2][wi];
        v4f vals;
#pragma unroll
        for (int e = 0; e < 4; ++e) {
          int l2 = l2b + e;
          float v = d0 * wc0[l2] + d1v * wc1[l2] + d2v * wc2[l2];
          v = v * swv + base;
          float s = (float)(x + e) * dx;
          int x0 = min((int)s, 15);
          int x1 = min(x0 + 1, 15);
          float wx = s - (float)x0;
          vals[e] = v + srow[x0] + (srow[x1] - srow[x0]) * wx;
        }
        __builtin_nontemporal_store(vals, (v4f*)&out[obase + x]);
      }
    }
  }
}

struct MegaP {
  const float *x, *patch_w, *patch_b, *pos;
  const float *ln1w, *ln1b, *qkvw, *projw, *projb, *rpb, *ln2w, *ln2b;
  const float *fc1w, *fc1b, *fc2w, *fc2b;
  const float *skipw, *skipbi, *dt1w, *dt1b, *bn1w, *bn1b, *dt2w, *dt2b, *bn2w, *bn2b;
  float *out, *ws;
  unsigned *cnt, *flag;
};

// whole network: 1 dispatch, 62 fence-free grid barriers.
__launch_bounds__(256)
__global__ void swin_mega(MegaP p) {
  __shared__ SMem sm;
  unsigned gen = 0;

  float* h    = p.ws;                // 98304   (256 x 384, "buggy-flatten" layout)
  float* qkvb = p.ws + 98304;        // 294912
  float* obuf = p.ws + 393216;       // 98304
  float* zb   = p.ws + 491520;       // 393216
  float* d1b  = p.ws + 884736;       // 196608
  float* skb  = p.ws + 1081344;      // 1024

  // patch embed: M=256 (h,w), N=384 (c), K=768; transposed store + pos add
  gemm_stage<2, 2, 2, 2, false, 3>(sm, p.x, p.patch_w, p.patch_b, nullptr, nullptr,
                                   nullptr, p.pos, h, 384, 768);
  gridbar(p.cnt, p.flag, gen);

#pragma unroll 1
  for (int b = 0; b < 12; ++b) {
    // qkv: LN1 + window-shift rows, N=1152, K=384 (144 tiles)
    gemm_stage<2, 2, 2, 1, true, 0>(sm, h, p.qkvw + (size_t)b * 442368, nullptr,
                                    p.ln1w + b * 384, p.ln1b + b * 384,
                                    nullptr, nullptr, qkvb, 1152, 384);
    gridbar(p.cnt, p.flag, gen);
    attn_stage(sm, qkvb, p.rpb + b * 2700, obuf);
    gridbar(p.cnt, p.flag, gen);
    // proj: + bias + residual(h) -> h (96 tiles)
    gemm_stage<1, 4, 1, 0, false, 1>(sm, obuf, p.projw + (size_t)b * 147456,
                                     p.projb + b * 384, nullptr, nullptr,
                                     h, nullptr, h, 384, 384);
    gridbar(p.cnt, p.flag, gen);
    // fc1: LN2 + gelu, N=1536, K=384 (192 tiles)
    gemm_stage<2, 2, 2, 0, true, 2>(sm, h, p.fc1w + (size_t)b * 589824,
                                    p.fc1b + b * 1536, p.ln2w + b * 384, p.ln2b + b * 384,
                                    nullptr, nullptr, zb, 1536, 384);
    gridbar(p.cnt, p.flag, gen);
    // fc2: + bias + residual(h) -> h, N=384, K=1536 (96 tiles)
    gemm_stage<1, 4, 1, 0, false, 1>(sm, zb, p.fc2w + (size_t)b * 589824,
                                     p.fc2b + b * 384, nullptr, nullptr,
                                     h, nullptr, h, 384, 1536);
    gridbar(p.cnt, p.flag, gen);
  }

  dec1_stage(sm, h, p.dt1w, p.dt1b, p.bn1w, p.bn1b, d1b, p.skipw, p.skipbi, skb);
  gridbar(p.cnt, p.flag, gen);
  dec2_stage(sm, d1b, p.dt2w, p.dt2b, p.bn2w, p.bn2b, skb, p.out);
}

// barrier state lives in poisoned workspace -> must re-zero every replay.
__global__ void init_bar_k(unsigned* bar) {
  if (threadIdx.x < 96) bar[threadIdx.x] = 0;
}

extern "C" void kernel_launch(void* const* d_in, const int* in_sizes, int n_in,
                              void* d_out, int out_size, void* d_ws, size_t ws_size,
                              hipStream_t stream) {
  float* ws = (float*)d_ws;
  unsigned* bar = (unsigned*)(ws + 1082368);  // past skb

  MegaP p;
  p.x       = (const float*)d_in[0];
  p.patch_w = (const float*)d_in[1];
  p.patch_b = (const float*)d_in[2];
  p.pos     = (const float*)d_in[3];
  p.ln1w    = (const float*)d_in[4];
  p.ln1b    = (const float*)d_in[5];
  p.qkvw    = (const float*)d_in[6];
  p.projw   = (const float*)d_in[7];
  p.projb   = (const float*)d_in[8];
  p.rpb     = (const float*)d_in[9];
  p.ln2w    = (const float*)d_in[10];
  p.ln2b    = (const float*)d_in[11];
  p.fc1w    = (const float*)d_in[12];
  p.fc1b    = (const float*)d_in[13];
  p.fc2w    = (const float*)d_in[14];
  p.fc2b    = (const float*)d_in[15];
  p.skipw   = (const float*)d_in[16];
  p.skipbi  = (const float*)d_in[17];
  p.dt1w    = (const float*)d_in[18];
  p.dt1b    = (const float*)d_in[19];
  p.bn1w    = (const float*)d_in[20];
  p.bn1b    = (const float*)d_in[21];
  p.dt2w    = (const float*)d_in[22];
  p.dt2b    = (const float*)d_in[23];
  p.bn2w    = (const float*)d_in[24];
  p.bn2b    = (const float*)d_in[25];
  p.out = (float*)d_out;
  p.ws  = ws;
  p.cnt  = bar;
  p.flag = bar + 64;  // separate cachelines: arrive traffic vs poll traffic

  init_bar_k<<<1, 128, 0, stream>>>(bar);
  swin_mega<<<NWG, 256, 0, stream>>>(p);
}